// Round 1
// 461.599 us; speedup vs baseline: 1.0105x; 1.0105x over previous
//
#include <hip/hip_runtime.h>
#include <stdint.h>

// Problem constants: B=128, D=512, N_ENVS=4, k = int(0.1*512*512) = 26214.
#define D_DIM   512
#define DD      262144                    // D*D
#define DD4     65536                     // DD / 4 (float4 groups)
#define B_DIM   128
#define N_ENVS  4
#define K_SEL   26214
#define BDD     33554432u                 // B*D*D
#define NBLK    64                        // hist/gather blocks per env
#define CAP2    65536                     // max gathered pairs per env (byte-bin; expect ~28K)
#define CAP3    4096                      // max in-LDS pairs for final rank select (expect ~700)

// Native 16-byte vector type (legal operand for __builtin_nontemporal_store).
typedef float nfloat4 __attribute__((ext_vector_type(4)));

// ---- workspace layout (bytes) ----
// [0,32)        thrcut[4][2]  {threshold key, cutoff idx}       (lives at d_ws base)
// [64,96)       pk[4][2]      {prefix byte-bin, krem8}
// [128,144)     cnt8[4]
// [4096,+256K)  histp[NBLK][N_ENVS][256] u32  per-block partial hists
//               (plain stores, NOT atomics onto poison -> no memset needed)
// [512K,+2M)    pairs8[4][CAP2] (uint2)
#define PK_OFF      64
#define CNT_OFF     128
#define HISTP_OFF   4096
#define HISTP_BYTES (NBLK * N_ENVS * 256 * 4)            // 256 KiB
#define PAIRS_OFF   (512 * 1024)
#define PAIRS_BYTES ((size_t)N_ENVS * CAP2 * 8)          // 2 MiB
#define SEL_NEED    (PAIRS_OFF + PAIRS_BYTES)            // selection scratch footprint

// Order-preserving float->uint key: larger float <=> larger key.
__device__ __forceinline__ uint32_t fkey(float f) {
    uint32_t u = __float_as_uint(f);
    return (u & 0x80000000u) ? ~u : (u | 0x80000000u);
}
__device__ __forceinline__ float sigmoidf_(float x) {
    return 1.0f / (1.0f + __expf(-x));
}

// ---- M1: top-8-bit histogram of keys, per env. grid (64, 4) x 256. ----
// Writes per-block partial histograms (no global atomics, no pre-zero needed).
// Also zeroes cnt8 (stream-ordered before gather8 uses it).
__global__ __launch_bounds__(256) void hist8_kernel(
    const float* __restrict__ base, const float* __restrict__ deltas,
    uint32_t* __restrict__ histp, uint32_t* __restrict__ cnt8)
{
    int e = blockIdx.y;
    const float4* b4 = (const float4*)base;
    const float4* d4 = (const float4*)(deltas + (size_t)e * DD);
    __shared__ uint32_t s_h[256];
    int tid = threadIdx.x;
    s_h[tid] = 0;
    if (blockIdx.x == 0 && tid == 0) cnt8[e] = 0;
    __syncthreads();
    int g0 = blockIdx.x * 256 + tid;                 // float4 group
    #pragma unroll
    for (int r = 0; r < 4; ++r) {
        int g = g0 + r * 16384;                      // 64 blocks * 256 threads
        float4 bv = b4[g], dv = d4[g];
        atomicAdd(&s_h[fkey(bv.x + dv.x) >> 24], 1u);
        atomicAdd(&s_h[fkey(bv.y + dv.y) >> 24], 1u);
        atomicAdd(&s_h[fkey(bv.z + dv.z) >> 24], 1u);
        atomicAdd(&s_h[fkey(bv.w + dv.w) >> 24], 1u);
    }
    __syncthreads();
    // histp[blk][e][bin] -- coalesced store, coalesced per-j reads in gather8.
    histp[(blockIdx.x * N_ENVS + e) * 256 + tid] = s_h[tid];
}

// ---- M2: find byte-bin P + krem8; gather (key,idx) with key>>24==P. ----
// grid (64, 4) x 256. Keys kept in registers: ONE pass over the data.
__global__ __launch_bounds__(256) void gather8_kernel(
    const float* __restrict__ base, const float* __restrict__ deltas,
    const uint32_t* __restrict__ histp, uint32_t* __restrict__ pk,
    uint32_t* __restrict__ cnt8, uint2* __restrict__ pairs8)
{
    int e = blockIdx.y;
    const float4* b4 = (const float4*)base;
    const float4* d4 = (const float4*)(deltas + (size_t)e * DD);
    uint2* pp = pairs8 + (size_t)e * CAP2;
    __shared__ uint32_t s_h[256];
    __shared__ uint32_t s_scan[256];
    __shared__ uint32_t s_P, s_base;
    int tid = threadIdx.x;

    // Sum the 64 per-block partials for my bin (coalesced per j).
    uint32_t sum = 0;
    #pragma unroll 8
    for (int j = 0; j < NBLK; ++j)
        sum += histp[(j * N_ENVS + e) * 256 + tid];
    s_h[tid] = sum;
    __syncthreads();
    if (tid == 0) {
        uint32_t cum = 0;
        for (int b = 255; b >= 0; --b) {
            uint32_t c = s_h[b];
            if (cum + c >= (uint32_t)K_SEL) {
                s_P = (uint32_t)b;
                if (blockIdx.x == 0) {
                    pk[2 * e + 0] = (uint32_t)b;
                    pk[2 * e + 1] = (uint32_t)K_SEL - cum;   // krem8 >= 1
                }
                break;
            }
            cum += c;
        }
    }
    __syncthreads();
    uint32_t P = s_P;

    // Phase 1: compute keys once, keep in registers, count my matches.
    int g0 = blockIdx.x * 256 + tid;
    uint32_t keys[16];
    uint32_t m = 0;
    #pragma unroll
    for (int r = 0; r < 4; ++r) {
        int g = g0 + r * 16384;
        float4 bv = b4[g], dv = d4[g];
        uint32_t k0 = fkey(bv.x + dv.x), k1 = fkey(bv.y + dv.y);
        uint32_t k2 = fkey(bv.z + dv.z), k3 = fkey(bv.w + dv.w);
        keys[r * 4 + 0] = k0; keys[r * 4 + 1] = k1;
        keys[r * 4 + 2] = k2; keys[r * 4 + 3] = k3;
        m += ((k0 >> 24) == P) + ((k1 >> 24) == P)
           + ((k2 >> 24) == P) + ((k3 >> 24) == P);
    }
    // Inclusive Hillis-Steele scan over 256 threads.
    s_scan[tid] = m;
    __syncthreads();
    #pragma unroll
    for (int off = 1; off < 256; off <<= 1) {
        uint32_t v = (tid >= off) ? s_scan[tid - off] : 0u;
        __syncthreads();
        s_scan[tid] += v;
        __syncthreads();
    }
    uint32_t excl = s_scan[tid] - m;
    if (tid == 255) s_base = atomicAdd(&cnt8[e], s_scan[255]);
    __syncthreads();
    uint32_t pos = s_base + excl;

    // Phase 2: scatter straight from registers (no re-read, no re-fkey).
    #pragma unroll
    for (int r = 0; r < 4; ++r) {
        int g = g0 + r * 16384;
        #pragma unroll
        for (int j = 0; j < 4; ++j) {
            uint32_t key = keys[r * 4 + j];
            if ((key >> 24) == P) {
                if (pos < CAP2) pp[pos] = make_uint2(key, (uint32_t)(g * 4 + j));
                ++pos;
            }
        }
    }
}

// ---- M3: refine within byte-bin (bits 16-23), gather sub-bin to LDS, ----
// ---- exact rank select (key desc, idx asc). grid 4 x 1024. ----
__global__ __launch_bounds__(1024) void select2_kernel(
    const uint32_t* __restrict__ pk, const uint32_t* __restrict__ cnt8,
    const uint2* __restrict__ pairs8, uint32_t* __restrict__ thrcut)
{
    int e = blockIdx.x;
    const uint2* pp = pairs8 + (size_t)e * CAP2;
    uint32_t M = cnt8[e]; if (M > CAP2) M = CAP2;
    uint32_t krem8 = pk[2 * e + 1];

    __shared__ uint32_t s_h16[256];
    __shared__ uint2    s_pairs[CAP3];
    __shared__ uint32_t s_b16, s_krem16, s_cnt;
    int tid = threadIdx.x;
    if (tid < 256) s_h16[tid] = 0;
    if (tid == 0) s_cnt = 0;
    __syncthreads();

    for (uint32_t j = tid; j < M; j += 1024)
        atomicAdd(&s_h16[(pp[j].x >> 16) & 255u], 1u);
    __syncthreads();
    if (tid == 0) {
        uint32_t cum = 0;
        for (int b = 255; b >= 0; --b) {
            uint32_t c = s_h16[b];
            if (cum + c >= krem8) { s_b16 = (uint32_t)b; s_krem16 = krem8 - cum; break; }
            cum += c;
        }
    }
    __syncthreads();
    uint32_t b16 = s_b16;
    for (uint32_t j = tid; j < M; j += 1024) {
        uint2 p = pp[j];
        if (((p.x >> 16) & 255u) == b16) {
            uint32_t pos = atomicAdd(&s_cnt, 1u);
            if (pos < CAP3) s_pairs[pos] = p;
        }
    }
    __syncthreads();
    uint32_t M2 = s_cnt; if (M2 > CAP3) M2 = CAP3;
    uint32_t target = s_krem16 - 1;                  // 0-based rank
    for (uint32_t j = tid; j < M2; j += 1024) {
        uint2 me = s_pairs[j];
        uint32_t rank = 0;
        for (uint32_t l = 0; l < M2; ++l) {
            uint2 o = s_pairs[l];
            rank += (o.x > me.x) || (o.x == me.x && o.y < me.y);
        }
        if (rank == target) {
            thrcut[2 * e + 0] = me.x;
            thrcut[2 * e + 1] = me.y;
        }
    }
}

// ---- M4: fused per-row compute + write of all 3 tensors. ----
// grid (128, 128) x 256; 2 float4 groups per thread, NT stores.
// Reads base+deltas (5 MB unique, L2-resident) instead of a 12 MB plane
// buffer; sigmoid recompute (~4 us of VALU) hides under 402 MB of writes.
__global__ __launch_bounds__(256) void fused_write_kernel(
    const int* __restrict__ env_idx, const float* __restrict__ base,
    const float* __restrict__ deltas, const uint32_t* __restrict__ thrcut,
    float* __restrict__ out)
{
    int b = blockIdx.y;
    int e = env_idx[b];
    uint32_t T = thrcut[2 * e], C = thrcut[2 * e + 1];
    const float4* b4 = (const float4*)base;
    const float4* d4 = (const float4*)(deltas + (size_t)e * DD);
    nfloat4* o4 = (nfloat4*)out + (size_t)b * DD4;
    int g0 = blockIdx.x * 512 + threadIdx.x;
    #pragma unroll
    for (int r = 0; r < 2; ++r) {
        int g = g0 + r * 256;
        uint32_t i0 = (uint32_t)g * 4u;
        float4 bv = b4[g];
        float4 dv = d4[g];
        nfloat4 lg = { bv.x + dv.x, bv.y + dv.y, bv.z + dv.z, bv.w + dv.w };
        nfloat4 sg = { sigmoidf_(lg.x), sigmoidf_(lg.y),
                       sigmoidf_(lg.z), sigmoidf_(lg.w) };
        uint32_t kx = fkey(lg.x), ky = fkey(lg.y), kz = fkey(lg.z), kw = fkey(lg.w);
        nfloat4 av;
        av.x = (kx > T || (kx == T && i0 + 0u <= C)) ? sg.x : 0.0f;
        av.y = (ky > T || (ky == T && i0 + 1u <= C)) ? sg.y : 0.0f;
        av.z = (kz > T || (kz == T && i0 + 2u <= C)) ? sg.z : 0.0f;
        av.w = (kw > T || (kw == T && i0 + 3u <= C)) ? sg.w : 0.0f;
        __builtin_nontemporal_store(av, o4 + g);
        __builtin_nontemporal_store(lg, o4 + g + (BDD / 4));
        __builtin_nontemporal_store(sg, o4 + g + 2ull * (BDD / 4));
    }
}

extern "C" void kernel_launch(void* const* d_in, const int* in_sizes, int n_in,
                              void* d_out, int out_size, void* d_ws, size_t ws_size,
                              hipStream_t stream) {
    // inputs: 0=z_s (unused), 1=env_idx (int32), 2=A_base (f32), 3=A_deltas (f32)
    const int*   env_idx  = (const int*)d_in[1];
    const float* A_base   = (const float*)d_in[2];
    const float* A_deltas = (const float*)d_in[3];
    float* out = (float*)d_out;

    uint32_t* thrcut = (uint32_t*)d_ws;   // 32 B, must survive to the fused write

    char* scratch;
    if (ws_size >= SEL_NEED) {
        scratch = (char*)d_ws;
    } else {
        // Carve selection scratch from d_out's tail; it is dead before the
        // fused write rewrites every output element (stream-ordered).
        size_t out_bytes = (size_t)out_size * sizeof(float);
        scratch = (char*)d_out + ((out_bytes - SEL_NEED) & ~(size_t)255);
    }
    uint32_t* pk     = (uint32_t*)(scratch + PK_OFF);
    uint32_t* cnt8   = (uint32_t*)(scratch + CNT_OFF);
    uint32_t* histp  = (uint32_t*)(scratch + HISTP_OFF);
    uint2*    pairs8 = (uint2*)   (scratch + PAIRS_OFF);

    // No memset: histp is written with plain stores (per-block partials),
    // cnt8 is zeroed by hist8 (stream-ordered before gather8),
    // pk/thrcut are written unconditionally every run.
    hist8_kernel  <<<dim3(NBLK, N_ENVS), 256, 0, stream>>>(A_base, A_deltas,
                                                           histp, cnt8);
    gather8_kernel<<<dim3(NBLK, N_ENVS), 256, 0, stream>>>(A_base, A_deltas, histp,
                                                           pk, cnt8, pairs8);
    select2_kernel<<<N_ENVS, 1024, 0, stream>>>(pk, cnt8, pairs8, thrcut);
    fused_write_kernel<<<dim3(DD4 / 512, B_DIM), 256, 0, stream>>>(
        env_idx, A_base, A_deltas, thrcut, out);
}

// Round 2
// 456.295 us; speedup vs baseline: 1.0222x; 1.0116x over previous
//
#include <hip/hip_runtime.h>
#include <stdint.h>

// Problem constants: B=128, D=512, N_ENVS=4, k = int(0.1*512*512) = 26214.
#define D_DIM   512
#define DD      262144                    // D*D
#define DD4     65536                     // DD / 4 (float4 groups)
#define B_DIM   128
#define N_ENVS  4
#define K_SEL   26214
#define BDD     33554432u                 // B*D*D
#define NBLK    64                        // hist/gather blocks per env
#define CAP2    98304                     // max gathered pairs per env
                                          // (threshold byte-bin of N(0,0.1) holds ~68K — 64K was at the cap)
#define CAP3    4096                      // max in-LDS pairs for final rank select (expect ~400)

// Native 16-byte vector type.
typedef float nfloat4 __attribute__((ext_vector_type(4)));

// ---- workspace layout (bytes) ----
// [0,32)        thrcut[4][2]  {threshold key, cutoff idx}       (lives at d_ws base)
// [64,96)       pk[4][2]      {prefix byte-bin, krem8}
// [128,144)     cnt8[4]
// [4096,+256K)  histp[NBLK][N_ENVS][256] u32  per-block partial hists
//               (plain stores, NOT atomics onto poison -> no memset needed)
// [512K,+3M)    pairs8[4][CAP2] (uint2)
#define PK_OFF      64
#define CNT_OFF     128
#define HISTP_OFF   4096
#define PAIRS_OFF   (512 * 1024)
#define PAIRS_BYTES ((size_t)N_ENVS * CAP2 * 8)          // 3 MiB
#define SEL_NEED    (PAIRS_OFF + PAIRS_BYTES)            // selection scratch footprint

// Order-preserving float->uint key: larger float <=> larger key.
__device__ __forceinline__ uint32_t fkey(float f) {
    uint32_t u = __float_as_uint(f);
    return (u & 0x80000000u) ? ~u : (u | 0x80000000u);
}
__device__ __forceinline__ float sigmoidf_(float x) {
    return 1.0f / (1.0f + __expf(-x));
}

// ---- M1: top-8-bit histogram of keys, per env. grid (64, 4) x 256. ----
// Writes per-block partial histograms (no global atomics, no pre-zero needed).
// Also zeroes cnt8 (stream-ordered before gather8 uses it).
__global__ __launch_bounds__(256) void hist8_kernel(
    const float* __restrict__ base, const float* __restrict__ deltas,
    uint32_t* __restrict__ histp, uint32_t* __restrict__ cnt8)
{
    int e = blockIdx.y;
    const float4* b4 = (const float4*)base;
    const float4* d4 = (const float4*)(deltas + (size_t)e * DD);
    __shared__ uint32_t s_h[256];
    int tid = threadIdx.x;
    s_h[tid] = 0;
    if (blockIdx.x == 0 && tid == 0) cnt8[e] = 0;
    __syncthreads();
    int g0 = blockIdx.x * 256 + tid;                 // float4 group
    #pragma unroll
    for (int r = 0; r < 4; ++r) {
        int g = g0 + r * 16384;                      // 64 blocks * 256 threads
        float4 bv = b4[g], dv = d4[g];
        atomicAdd(&s_h[fkey(bv.x + dv.x) >> 24], 1u);
        atomicAdd(&s_h[fkey(bv.y + dv.y) >> 24], 1u);
        atomicAdd(&s_h[fkey(bv.z + dv.z) >> 24], 1u);
        atomicAdd(&s_h[fkey(bv.w + dv.w) >> 24], 1u);
    }
    __syncthreads();
    // histp[blk][e][bin] -- coalesced store, coalesced per-j reads in gather8.
    histp[(blockIdx.x * N_ENVS + e) * 256 + tid] = s_h[tid];
}

// ---- M2: find byte-bin P + krem8; gather (key,idx) with key>>24==P. ----
// grid (64, 4) x 256. Keys kept in registers: ONE pass over the data.
__global__ __launch_bounds__(256) void gather8_kernel(
    const float* __restrict__ base, const float* __restrict__ deltas,
    const uint32_t* __restrict__ histp, uint32_t* __restrict__ pk,
    uint32_t* __restrict__ cnt8, uint2* __restrict__ pairs8)
{
    int e = blockIdx.y;
    const float4* b4 = (const float4*)base;
    const float4* d4 = (const float4*)(deltas + (size_t)e * DD);
    uint2* pp = pairs8 + (size_t)e * CAP2;
    __shared__ uint32_t s_h[256];
    __shared__ uint32_t s_scan[256];
    __shared__ uint32_t s_P, s_base;
    int tid = threadIdx.x;

    // Sum the 64 per-block partials for my bin (coalesced per j).
    uint32_t sum = 0;
    #pragma unroll 8
    for (int j = 0; j < NBLK; ++j)
        sum += histp[(j * N_ENVS + e) * 256 + tid];
    s_h[tid] = sum;
    __syncthreads();
    if (tid == 0) {
        uint32_t cum = 0;
        for (int b = 255; b >= 0; --b) {
            uint32_t c = s_h[b];
            if (cum + c >= (uint32_t)K_SEL) {
                s_P = (uint32_t)b;
                if (blockIdx.x == 0) {
                    pk[2 * e + 0] = (uint32_t)b;
                    pk[2 * e + 1] = (uint32_t)K_SEL - cum;   // krem8 >= 1
                }
                break;
            }
            cum += c;
        }
    }
    __syncthreads();
    uint32_t P = s_P;

    // Phase 1: compute keys once, keep in registers, count my matches.
    int g0 = blockIdx.x * 256 + tid;
    uint32_t keys[16];
    uint32_t m = 0;
    #pragma unroll
    for (int r = 0; r < 4; ++r) {
        int g = g0 + r * 16384;
        float4 bv = b4[g], dv = d4[g];
        uint32_t k0 = fkey(bv.x + dv.x), k1 = fkey(bv.y + dv.y);
        uint32_t k2 = fkey(bv.z + dv.z), k3 = fkey(bv.w + dv.w);
        keys[r * 4 + 0] = k0; keys[r * 4 + 1] = k1;
        keys[r * 4 + 2] = k2; keys[r * 4 + 3] = k3;
        m += ((k0 >> 24) == P) + ((k1 >> 24) == P)
           + ((k2 >> 24) == P) + ((k3 >> 24) == P);
    }
    // Inclusive Hillis-Steele scan over 256 threads.
    s_scan[tid] = m;
    __syncthreads();
    #pragma unroll
    for (int off = 1; off < 256; off <<= 1) {
        uint32_t v = (tid >= off) ? s_scan[tid - off] : 0u;
        __syncthreads();
        s_scan[tid] += v;
        __syncthreads();
    }
    uint32_t excl = s_scan[tid] - m;
    if (tid == 255) s_base = atomicAdd(&cnt8[e], s_scan[255]);
    __syncthreads();
    uint32_t pos = s_base + excl;

    // Phase 2: scatter straight from registers (no re-read, no re-fkey).
    #pragma unroll
    for (int r = 0; r < 4; ++r) {
        int g = g0 + r * 16384;
        #pragma unroll
        for (int j = 0; j < 4; ++j) {
            uint32_t key = keys[r * 4 + j];
            if ((key >> 24) == P) {
                if (pos < CAP2) pp[pos] = make_uint2(key, (uint32_t)(g * 4 + j));
                ++pos;
            }
        }
    }
}

// ---- M3: refine within byte-bin (bits 16-23), gather sub-bin to LDS, ----
// ---- exact rank select (key desc, idx asc). grid 4 x 1024. ----
__global__ __launch_bounds__(1024) void select2_kernel(
    const uint32_t* __restrict__ pk, const uint32_t* __restrict__ cnt8,
    const uint2* __restrict__ pairs8, uint32_t* __restrict__ thrcut)
{
    int e = blockIdx.x;
    const uint2* pp = pairs8 + (size_t)e * CAP2;
    uint32_t M = cnt8[e]; if (M > CAP2) M = CAP2;
    uint32_t krem8 = pk[2 * e + 1];

    __shared__ uint32_t s_h16[256];
    __shared__ uint2    s_pairs[CAP3];
    __shared__ uint32_t s_b16, s_krem16, s_cnt;
    int tid = threadIdx.x;
    if (tid < 256) s_h16[tid] = 0;
    if (tid == 0) s_cnt = 0;
    __syncthreads();

    for (uint32_t j = tid; j < M; j += 1024)
        atomicAdd(&s_h16[(pp[j].x >> 16) & 255u], 1u);
    __syncthreads();
    if (tid == 0) {
        uint32_t cum = 0;
        for (int b = 255; b >= 0; --b) {
            uint32_t c = s_h16[b];
            if (cum + c >= krem8) { s_b16 = (uint32_t)b; s_krem16 = krem8 - cum; break; }
            cum += c;
        }
    }
    __syncthreads();
    uint32_t b16 = s_b16;
    for (uint32_t j = tid; j < M; j += 1024) {
        uint2 p = pp[j];
        if (((p.x >> 16) & 255u) == b16) {
            uint32_t pos = atomicAdd(&s_cnt, 1u);
            if (pos < CAP3) s_pairs[pos] = p;
        }
    }
    __syncthreads();
    uint32_t M2 = s_cnt; if (M2 > CAP3) M2 = CAP3;
    uint32_t target = s_krem16 - 1;                  // 0-based rank
    for (uint32_t j = tid; j < M2; j += 1024) {
        uint2 me = s_pairs[j];
        uint32_t rank = 0;
        for (uint32_t l = 0; l < M2; ++l) {
            uint2 o = s_pairs[l];
            rank += (o.x > me.x) || (o.x == me.x && o.y < me.y);
        }
        if (rank == target) {
            thrcut[2 * e + 0] = me.x;
            thrcut[2 * e + 1] = me.y;
        }
    }
}

// ---- M4: compute-once-per-env in registers, broadcast to rows. ----
// grid (256, 8) x 256. Each thread owns ONE float4 group; computes the
// (A, logits, soft) triple for all 4 envs into registers (48 VGPRs), then
// stores them to 16 output rows via a wave-uniform switch(env).
// Reads: 20 MB one-time (vs 268 MB re-read before). Stores: PLAIN (not nt)
// -- the rocclr fill proves plain 16B/lane stores sustain 6.2 TB/s; nt
// bypasses L2 write-combining and was the prime suspect for the ~2 TB/s
// drain observed in rounds 0-1.
__global__ __launch_bounds__(256) void write_bcast_kernel(
    const int* __restrict__ env_idx, const float* __restrict__ base,
    const float* __restrict__ deltas, const uint32_t* __restrict__ thrcut,
    float* __restrict__ out)
{
    int g = blockIdx.x * 256 + threadIdx.x;          // float4 group in [0, DD4)
    uint32_t i0 = (uint32_t)g * 4u;
    float4 bv = ((const float4*)base)[g];

    nfloat4 lgv[N_ENVS], sgv[N_ENVS], avv[N_ENVS];   // static indexing only
    #pragma unroll
    for (int e = 0; e < N_ENVS; ++e) {
        float4 dv = ((const float4*)(deltas + (size_t)e * DD))[g];
        uint32_t T = thrcut[2 * e], C = thrcut[2 * e + 1];
        nfloat4 lg = { bv.x + dv.x, bv.y + dv.y, bv.z + dv.z, bv.w + dv.w };
        nfloat4 sg = { sigmoidf_(lg.x), sigmoidf_(lg.y),
                       sigmoidf_(lg.z), sigmoidf_(lg.w) };
        uint32_t kx = fkey(lg.x), ky = fkey(lg.y);
        uint32_t kz = fkey(lg.z), kw = fkey(lg.w);
        nfloat4 av;
        av.x = (kx > T || (kx == T && i0 + 0u <= C)) ? sg.x : 0.0f;
        av.y = (ky > T || (ky == T && i0 + 1u <= C)) ? sg.y : 0.0f;
        av.z = (kz > T || (kz == T && i0 + 2u <= C)) ? sg.z : 0.0f;
        av.w = (kw > T || (kw == T && i0 + 3u <= C)) ? sg.w : 0.0f;
        lgv[e] = lg; sgv[e] = sg; avv[e] = av;
    }

    const int ROWS = B_DIM / 8;                      // 16 rows per y-block
    int b0 = blockIdx.y * ROWS;
    nfloat4* o0 = (nfloat4*)out + g;
    #pragma unroll 4
    for (int bb = 0; bb < ROWS; ++bb) {
        int b = b0 + bb;
        int e = env_idx[b];                          // wave-uniform
        nfloat4* o = o0 + (size_t)b * DD4;
        switch (e) {                                 // uniform branch, static reg idx
        case 0: o[0] = avv[0]; o[BDD/4] = lgv[0]; o[2*(BDD/4)] = sgv[0]; break;
        case 1: o[0] = avv[1]; o[BDD/4] = lgv[1]; o[2*(BDD/4)] = sgv[1]; break;
        case 2: o[0] = avv[2]; o[BDD/4] = lgv[2]; o[2*(BDD/4)] = sgv[2]; break;
        default: o[0] = avv[3]; o[BDD/4] = lgv[3]; o[2*(BDD/4)] = sgv[3]; break;
        }
    }
}

extern "C" void kernel_launch(void* const* d_in, const int* in_sizes, int n_in,
                              void* d_out, int out_size, void* d_ws, size_t ws_size,
                              hipStream_t stream) {
    // inputs: 0=z_s (unused), 1=env_idx (int32), 2=A_base (f32), 3=A_deltas (f32)
    const int*   env_idx  = (const int*)d_in[1];
    const float* A_base   = (const float*)d_in[2];
    const float* A_deltas = (const float*)d_in[3];
    float* out = (float*)d_out;

    uint32_t* thrcut = (uint32_t*)d_ws;   // 32 B, must survive to the final write

    char* scratch;
    if (ws_size >= SEL_NEED) {
        scratch = (char*)d_ws;
    } else {
        // Carve selection scratch from d_out's tail; it is dead before the
        // final write rewrites every output element (stream-ordered).
        size_t out_bytes = (size_t)out_size * sizeof(float);
        scratch = (char*)d_out + ((out_bytes - SEL_NEED) & ~(size_t)255);
    }
    uint32_t* pk     = (uint32_t*)(scratch + PK_OFF);
    uint32_t* cnt8   = (uint32_t*)(scratch + CNT_OFF);
    uint32_t* histp  = (uint32_t*)(scratch + HISTP_OFF);
    uint2*    pairs8 = (uint2*)   (scratch + PAIRS_OFF);

    // No memset: histp is written with plain stores (per-block partials),
    // cnt8 is zeroed by hist8 (stream-ordered before gather8),
    // pk/thrcut are written unconditionally every run.
    hist8_kernel  <<<dim3(NBLK, N_ENVS), 256, 0, stream>>>(A_base, A_deltas,
                                                           histp, cnt8);
    gather8_kernel<<<dim3(NBLK, N_ENVS), 256, 0, stream>>>(A_base, A_deltas, histp,
                                                           pk, cnt8, pairs8);
    select2_kernel<<<N_ENVS, 1024, 0, stream>>>(pk, cnt8, pairs8, thrcut);
    write_bcast_kernel<<<dim3(DD4 / 256, 8), 256, 0, stream>>>(
        env_idx, A_base, A_deltas, thrcut, out);
}